// Round 1
// baseline (578.780 us; speedup 1.0000x reference)
//
#include <hip/hip_runtime.h>

#define NN 8192
#define DD 256
#define FF 128
#define BB 4096
#define NSPLIT 16
#define KCHUNK (NN / NSPLIT)   // 512 keys per split-K chunk
#define NITER (KCHUNK / 64)    // 8 key-tiles per chunk

typedef unsigned short ushortT;
typedef __attribute__((ext_vector_type(8))) short bf16x8;
typedef __attribute__((ext_vector_type(4))) float f32x4;

__device__ __forceinline__ ushortT f2bf(float f) {   // fp32 -> bf16 RNE
  unsigned u = __float_as_uint(f);
  return (ushortT)((u + 0x7FFFu + ((u >> 16) & 1u)) >> 16);
}
__device__ __forceinline__ float bf2f(ushortT h) {
  return __uint_as_float(((unsigned)h) << 16);
}

// ---------------- unique(x) compaction ----------------

__global__ __launch_bounds__(256) void init_kernel(int* flags, int* cnt) {
  int i = blockIdx.x * 256 + threadIdx.x;
  flags[i] = 0;
  if (i == 0) *cnt = 0;
}

__global__ __launch_bounds__(256) void scatter_kernel(const int* __restrict__ x, int* flags) {
  int b = blockIdx.x * 256 + threadIdx.x;
  flags[x[b]] = 1;
}

__global__ __launch_bounds__(256) void compact_kernel(const int* __restrict__ flags, int* cnt,
                                                      int* list, int* slot) {
  int i = blockIdx.x * 256 + threadIdx.x;
  if (flags[i]) {
    int pos = atomicAdd(cnt, 1);
    list[pos] = i;
    slot[i] = pos;
  }
}

// ---------------- pack adj rows of unique slots into bitmasks ----------------
// pk[s][k/32] bit (k&31) = adj[list[s]][k] > 0.  ~3.3 MB replacing a 107 MB
// latency-critical HBM stream in attn.

__global__ __launch_bounds__(256) void pack_kernel(const int* __restrict__ adj,
                                                   const int* __restrict__ list,
                                                   const int* __restrict__ cntp,
                                                   unsigned* __restrict__ pk) {
  const int s = blockIdx.x >> 2;
  const int kc = (blockIdx.x & 3) * 2048;
  if (s >= *cntp) return;                    // uniform per block
  const int w = threadIdx.x >> 6, l = threadIdx.x & 63;
  const int* base = adj + (size_t)list[s] * NN + kc + w * 512;
  unsigned long long* dst = (unsigned long long*)(pk + s * 256 + (kc >> 5) + w * 16);
#pragma unroll
  for (int i = 0; i < 8; ++i) {
    unsigned long long b = __ballot(base[i * 64 + l] > 0);  // bit l = key ...+i*64+l
    if (l == 0) dst[i] = b;
  }
}

// ---------------- Wh = embedding @ W, emitted as bf16 hi/lo split ----------------

__global__ __launch_bounds__(256) void wh_kernel(const float* __restrict__ emb,
                                                 const float* __restrict__ W,
                                                 ushortT* __restrict__ Whh,
                                                 ushortT* __restrict__ Whl) {
  __shared__ float Es[32 * 65];
  __shared__ float Ws[64 * 128];
  const int t = threadIdx.x;
  const int r0 = blockIdx.x * 32;
  const int rg = t >> 5;
  const int cg = t & 31;
  float4 acc[4] = {{0,0,0,0},{0,0,0,0},{0,0,0,0},{0,0,0,0}};
  for (int kc = 0; kc < DD; kc += 64) {
    __syncthreads();
    for (int i = 0; i < 8; ++i) {
      int idx = t + 256 * i;
      int r = idx >> 6, k = idx & 63;
      Es[r * 65 + k] = emb[(r0 + r) * DD + kc + k];
    }
    for (int i = 0; i < 8; ++i) {
      int idx = t + 256 * i;
      int kr = idx >> 5, c4 = (idx & 31) * 4;
      *(float4*)&Ws[kr * 128 + c4] = *(const float4*)&W[(kc + kr) * 128 + c4];
    }
    __syncthreads();
    for (int k = 0; k < 64; ++k) {
      float4 b = *(const float4*)&Ws[k * 128 + cg * 4];
#pragma unroll
      for (int i = 0; i < 4; ++i) {
        float a = Es[(rg * 4 + i) * 65 + k];
        acc[i].x += a * b.x; acc[i].y += a * b.y;
        acc[i].z += a * b.z; acc[i].w += a * b.w;
      }
    }
  }
#pragma unroll
  for (int i = 0; i < 4; ++i) {
    int row = r0 + rg * 4 + i;
    float v[4] = {acc[i].x, acc[i].y, acc[i].z, acc[i].w};
    ushort4 hh, ll;
    ushortT* hp = (ushortT*)&hh;
    ushortT* lp = (ushortT*)&ll;
#pragma unroll
    for (int k = 0; k < 4; ++k) {
      ushortT h = f2bf(v[k]);
      hp[k] = h;
      lp[k] = f2bf(v[k] - bf2f(h));
    }
    *(ushort4*)&Whh[row * FF + cg * 4] = hh;
    *(ushort4*)&Whl[row * FF + cg * 4] = ll;
  }
}

// ---------------- WhT = Whh^T (128 x 8192), 64x64 tiles (256 blocks) ----------------

__global__ __launch_bounds__(256) void transpose_kernel(const ushortT* __restrict__ A,
                                                        ushortT* __restrict__ At) {
  __shared__ ushortT tile[64 * 72];      // chunk-swizzled: (r, cb) at r*72 + ((cb^((r>>3)&7))*8)
  const int t = threadIdx.x;
  const int r0 = (blockIdx.x >> 1) * 64, c0 = (blockIdx.x & 1) * 64;
#pragma unroll
  for (int i = 0; i < 2; ++i) {
    int idx = t + 256 * i;
    int r = idx >> 3, cb = idx & 7;
    *(bf16x8*)&tile[r * 72 + ((cb ^ ((r >> 3) & 7)) * 8)] =
        *(const bf16x8*)&A[(size_t)(r0 + r) * FF + c0 + cb * 8];
  }
  __syncthreads();
#pragma unroll
  for (int i = 0; i < 2; ++i) {
    int idx = t + 256 * i;
    int f = idx >> 3, r8 = idx & 7;
    bf16x8 v;
#pragma unroll
    for (int u = 0; u < 8; ++u) {
      int row = r8 * 8 + u;
      v[u] = (short)tile[row * 72 + (((f >> 3) ^ ((row >> 3) & 7)) * 8) + (f & 7)];
    }
    *(bf16x8*)&At[(size_t)(c0 + f) * NN + r0 + r8 * 8] = v;
  }
}

// ---------------- MFMA flash attention: barrier-free, K direct from L2 ----------------
// Block = 256 thr = 4 waves, 64 q-rows (wave w: rows w*16..+15), one 512-key chunk.
// NO K LDS staging: QK^T B-frags (hi+lo) are read per-lane straight from Whh/Whl —
// a 16x16x32 B-frag is 16 contiguous bytes of one K row, so each load instruction
// touches 16 rows x 64 B, served by the per-XCD L2 (chunk-major block order keeps
// each XCD on 2 chunks: K+V+pk+Q hot set ~2.9 MB < 4 MB L2). LDS holds only the
// per-wave Ps transpose buffer (9.5 KB) -> no __syncthreads in the main loop, and
// __launch_bounds__(256,3) + NSPLIT=16 (816 active blocks) gives ~3 waves/SIMD of
// pure TLP instead of 1.6 barrier-convoyed waves.
// MFMA term order per (nt,ks) is IDENTICAL to the previous version (qh*bh, ql*bh,
// qh*bl) so the numerics are unchanged.
// Layouts: A[m=lane&15][k=quad*8+j]; B[k=quad*8+j][n=lane&15]; C/D row=quad*4+reg, col=lane&15.

__global__ __launch_bounds__(256, 3) void attn_kernel(
    const ushortT* __restrict__ Whh, const ushortT* __restrict__ Whl,
    const ushortT* __restrict__ WhT, const unsigned* __restrict__ pk,
    const int* __restrict__ list, const int* __restrict__ cntp,
    float* __restrict__ Opart, float* __restrict__ mpart, float* __restrict__ lpart) {
  __shared__ short Ps[4][16 * 72];
  __shared__ int nid[64];

  const int cnt = *cntp;
  const int qblk = blockIdx.x >> 4, chunk = blockIdx.x & 15;
  const int q0 = qblk * 64;
  if (q0 >= cnt) return;                 // uniform: whole block exits

  const int t = threadIdx.x;
  if (t < 64) nid[t] = list[min(q0 + t, cnt - 1)];  // tail rows dup cnt-1 (junk slots unused)
  __syncthreads();

  const int w = t >> 6, l = t & 63, quad = l >> 4, c = l & 15;

  // Q fragments in registers for the whole K loop (A-operand: row = c)
  const size_t qr = (size_t)nid[w * 16 + c] * FF;
  bf16x8 qh[4], ql[4];
#pragma unroll
  for (int ks = 0; ks < 4; ++ks) {
    qh[ks] = *(const bf16x8*)(Whh + qr + ks * 32 + quad * 8);
    ql[ks] = *(const bf16x8*)(Whl + qr + ks * 32 + quad * 8);
  }
  int prow[4];
#pragma unroll
  for (int r = 0; r < 4; ++r) prow[r] = min(q0 + w * 16 + quad * 4 + r, cnt - 1);

  float m[4], lr[4];
#pragma unroll
  for (int r = 0; r < 4; ++r) { m[r] = -1e30f; lr[r] = 0.f; }
  f32x4 O[8] = {{0,0,0,0},{0,0,0,0},{0,0,0,0},{0,0,0,0},
                {0,0,0,0},{0,0,0,0},{0,0,0,0},{0,0,0,0}};

  const int kt0 = chunk * KCHUNK;

  for (int it = 0; it < NITER; ++it) {
    const int kt = kt0 + it * 64;

    // ---- mask words: 64 bits per row, broadcast loads (L2) ----
    unsigned mw0[4], mw1[4];
#pragma unroll
    for (int r = 0; r < 4; ++r) {
      uint2 mm = *(const uint2*)(pk + (size_t)prow[r] * 256 + (kt >> 5));
      mw0[r] = mm.x; mw1[r] = mm.y;
    }

    // ---- S = Q.K^T over 4 key-16 tiles, 3-term hi/lo, K direct from global (L2) ----
    f32x4 sacc[4];
#pragma unroll
    for (int nt = 0; nt < 4; ++nt) {
      const ushortT* kh = Whh + (size_t)(kt + nt * 16 + c) * FF + quad * 8;
      const ushortT* kl = Whl + (size_t)(kt + nt * 16 + c) * FF + quad * 8;
      f32x4 a = {0, 0, 0, 0};
#pragma unroll
      for (int ks = 0; ks < 4; ++ks) {
        bf16x8 bh = *(const bf16x8*)(kh + ks * 32);
        bf16x8 bl = *(const bf16x8*)(kl + ks * 32);
        a = __builtin_amdgcn_mfma_f32_16x16x32_bf16(qh[ks], bh, a, 0, 0, 0);
        a = __builtin_amdgcn_mfma_f32_16x16x32_bf16(ql[ks], bh, a, 0, 0, 0);
        a = __builtin_amdgcn_mfma_f32_16x16x32_bf16(qh[ks], bl, a, 0, 0, 0);
      }
      sacc[nt] = a;
    }

    // ---- in-wave masked online softmax ----
    float rmax[4];
#pragma unroll
    for (int r = 0; r < 4; ++r) {
      float v = -1e30f;
#pragma unroll
      for (int nt = 0; nt < 4; ++nt) {
        unsigned bit = ((nt < 2 ? mw0[r] : mw1[r]) >> ((nt & 1) * 16 + c)) & 1u;
        v = fmaxf(v, bit ? sacc[nt][r] : -1e30f);
      }
      rmax[r] = v;
    }
#pragma unroll
    for (int mk = 1; mk <= 8; mk <<= 1)
#pragma unroll
      for (int r = 0; r < 4; ++r) rmax[r] = fmaxf(rmax[r], __shfl_xor(rmax[r], mk, 16));
    float sc[4], psum[4];
#pragma unroll
    for (int r = 0; r < 4; ++r) {
      float nm = fmaxf(m[r], rmax[r]);
      sc[r] = __expf(m[r] - nm);
      m[r] = nm;
      psum[r] = 0.f;
    }
#pragma unroll
    for (int nt = 0; nt < 4; ++nt)
#pragma unroll
      for (int r = 0; r < 4; ++r) {
        unsigned bit = ((nt < 2 ? mw0[r] : mw1[r]) >> ((nt & 1) * 16 + c)) & 1u;
        float p = bit ? __expf(sacc[nt][r] - m[r]) : 0.f;
        ushortT pb = f2bf(p);
        Ps[w][(quad * 4 + r) * 72 + nt * 16 + c] = (short)pb;
        psum[r] += bf2f(pb);
      }
#pragma unroll
    for (int mk = 1; mk <= 8; mk <<= 1)
#pragma unroll
      for (int r = 0; r < 4; ++r) psum[r] += __shfl_xor(psum[r], mk, 16);
#pragma unroll
    for (int r = 0; r < 4; ++r) lr[r] = lr[r] * sc[r] + psum[r];

    // ---- O rescale + PV (A from per-wave Ps, B from WhT global) ----
#pragma unroll
    for (int ft = 0; ft < 8; ++ft)
#pragma unroll
      for (int r = 0; r < 4; ++r) O[ft][r] *= sc[r];
    bf16x8 pa[2];
#pragma unroll
    for (int ks2 = 0; ks2 < 2; ++ks2)
      pa[ks2] = *(const bf16x8*)&Ps[w][c * 72 + ks2 * 32 + quad * 8];
#pragma unroll
    for (int ft = 0; ft < 8; ++ft) {
      const ushortT* vp = WhT + (size_t)(ft * 16 + c) * NN + kt + quad * 8;
#pragma unroll
      for (int ks2 = 0; ks2 < 2; ++ks2) {
        bf16x8 vb = *(const bf16x8*)(vp + ks2 * 32);
        O[ft] = __builtin_amdgcn_mfma_f32_16x16x32_bf16(pa[ks2], vb, O[ft], 0, 0, 0);
      }
    }
  }

  // ---- epilogue ----
  float* Op = Opart + (size_t)chunk * 4096 * FF;
#pragma unroll
  for (int ft = 0; ft < 8; ++ft)
#pragma unroll
    for (int r = 0; r < 4; ++r)
      Op[(size_t)(q0 + w * 16 + quad * 4 + r) * FF + ft * 16 + c] = O[ft][r];
  if (c == 0) {
#pragma unroll
    for (int r = 0; r < 4; ++r) {
      mpart[chunk * 4096 + q0 + w * 16 + quad * 4 + r] = m[r];
      lpart[chunk * 4096 + q0 + w * 16 + quad * 4 + r] = lr[r];
    }
  }
}

// ---------------- merge split-K partials, normalize, elu ----------------

__global__ __launch_bounds__(128) void combine_kernel(
    const float* __restrict__ Opart, const float* __restrict__ mpart,
    const float* __restrict__ lpart, float* __restrict__ h) {
  const int r = blockIdx.x;
  const int t = threadIdx.x;
  float mstar = -1e30f;
#pragma unroll
  for (int c = 0; c < NSPLIT; ++c) mstar = fmaxf(mstar, mpart[c * 4096 + r]);
  float lstar = 0.f, acc = 0.f;
#pragma unroll
  for (int c = 0; c < NSPLIT; ++c) {
    float wgt = __expf(mpart[c * 4096 + r] - mstar);
    lstar += wgt * lpart[c * 4096 + r];
    acc += wgt * Opart[((size_t)c * 4096 + r) * FF + t];
  }
  float v = acc / fmaxf(lstar, 1e-30f);
  h[r * FF + t] = v > 0.f ? v : expm1f(v);
}

// ---------------- gather by x, L2-normalize ----------------

__global__ __launch_bounds__(128) void out_kernel(const int* __restrict__ x,
                                                  const int* __restrict__ slot,
                                                  const float* __restrict__ h,
                                                  float* __restrict__ out) {
  const int b = blockIdx.x, t = threadIdx.x;
  const int s = slot[x[b]];
  float v = h[s * FF + t];
  float ss = v * v;
#pragma unroll
  for (int wd = 1; wd <= 32; wd <<= 1) ss += __shfl_xor(ss, wd);
  __shared__ float red[2];
  if ((t & 63) == 0) red[t >> 6] = ss;
  __syncthreads();
  float tot = red[0] + red[1];
  float scale = 1.f / fmaxf(sqrtf(tot), 1e-12f);
  out[b * FF + t] = v * scale;
}

// ---------------- launch ----------------

extern "C" void kernel_launch(void* const* d_in, const int* in_sizes, int n_in,
                              void* d_out, int out_size, void* d_ws, size_t ws_size,
                              hipStream_t stream) {
  const int*   x   = (const int*)d_in[0];
  const int*   adj = (const int*)d_in[1];
  const float* emb = (const float*)d_in[2];
  const float* W   = (const float*)d_in[3];
  float* out = (float*)d_out;

  char* base = (char*)d_ws;                              // ~44.6 MB total
  ushortT* Whh = (ushortT*)(base);                       //  0 .. 2 MB
  ushortT* Whl = (ushortT*)(base + 2097152);             //  2 .. 4 MB (dead after attn)
  float*   h   = (float*)(base + 2097152);               //  aliases Whl
  ushortT* WhT = (ushortT*)(base + 4194304);             //  4 .. 6 MB
  float* Opart = (float*)(base + 6291456);               //  6 .. 39.55 MB (16 chunks)
  float* mpart = (float*)(base + 39845888);
  float* lpart = (float*)(base + 40108032);
  unsigned* pk = (unsigned*)(base + 40370176);           //  4 MB packed adj bits
  int*   flags = (int*)(base + 44564480);
  int*   list  = (int*)(base + 44597248);
  int*   slot  = (int*)(base + 44613632);
  int*   cnt   = (int*)(base + 44646400);
  (void)in_sizes; (void)n_in; (void)out_size; (void)ws_size;

  hipLaunchKernelGGL(init_kernel,      dim3(NN / 256), dim3(256), 0, stream, flags, cnt);
  hipLaunchKernelGGL(scatter_kernel,   dim3(BB / 256), dim3(256), 0, stream, x, flags);
  hipLaunchKernelGGL(compact_kernel,   dim3(NN / 256), dim3(256), 0, stream, flags, cnt, list, slot);
  hipLaunchKernelGGL(pack_kernel,      dim3(4096 * 4), dim3(256), 0, stream, adj, list, cnt, pk);
  hipLaunchKernelGGL(wh_kernel,        dim3(NN / 32),  dim3(256), 0, stream, emb, W, Whh, Whl);
  hipLaunchKernelGGL(transpose_kernel, dim3((NN / 64) * 2), dim3(256), 0, stream, Whh, WhT);
  hipLaunchKernelGGL(attn_kernel,      dim3((BB / 64) * NSPLIT), dim3(256), 0, stream,
                     Whh, Whl, WhT, pk, list, cnt, Opart, mpart, lpart);
  hipLaunchKernelGGL(combine_kernel,   dim3(4096), dim3(128), 0, stream, Opart, mpart, lpart, h);
  hipLaunchKernelGGL(out_kernel,       dim3(BB),   dim3(128), 0, stream, x, slot, h, out);
}

// Round 2
// 492.239 us; speedup vs baseline: 1.1758x; 1.1758x over previous
//
#include <hip/hip_runtime.h>

#define NN 8192
#define DD 256
#define FF 128
#define BB 4096
#define NSPLIT 16
#define KCHUNK (NN / NSPLIT)   // 512 keys per split-K chunk
#define NITER (KCHUNK / 64)    // 8 key-tiles per chunk

typedef unsigned short ushortT;
typedef __attribute__((ext_vector_type(8))) short bf16x8;
typedef __attribute__((ext_vector_type(4))) float f32x4;

__device__ __forceinline__ ushortT f2bf(float f) {   // fp32 -> bf16 RNE
  unsigned u = __float_as_uint(f);
  return (ushortT)((u + 0x7FFFu + ((u >> 16) & 1u)) >> 16);
}
__device__ __forceinline__ float bf2f(ushortT h) {
  return __uint_as_float(((unsigned)h) << 16);
}

// ---------------- unique(x) compaction ----------------

__global__ __launch_bounds__(256) void init_kernel(int* flags, int* cnt) {
  int i = blockIdx.x * 256 + threadIdx.x;
  flags[i] = 0;
  if (i == 0) *cnt = 0;
}

__global__ __launch_bounds__(256) void scatter_kernel(const int* __restrict__ x, int* flags) {
  int b = blockIdx.x * 256 + threadIdx.x;
  flags[x[b]] = 1;
}

__global__ __launch_bounds__(256) void compact_kernel(const int* __restrict__ flags, int* cnt,
                                                      int* list, int* slot) {
  int i = blockIdx.x * 256 + threadIdx.x;
  if (flags[i]) {
    int pos = atomicAdd(cnt, 1);
    list[pos] = i;
    slot[i] = pos;
  }
}

// ---------------- pack adj rows of unique slots into bitmasks ----------------
// pk[s][k/32] bit (k&31) = adj[list[s]][k] > 0.  ~3.3 MB replacing a 107 MB
// latency-critical HBM stream in attn.

__global__ __launch_bounds__(256) void pack_kernel(const int* __restrict__ adj,
                                                   const int* __restrict__ list,
                                                   const int* __restrict__ cntp,
                                                   unsigned* __restrict__ pk) {
  const int s = blockIdx.x >> 2;
  const int kc = (blockIdx.x & 3) * 2048;
  if (s >= *cntp) return;                    // uniform per block
  const int w = threadIdx.x >> 6, l = threadIdx.x & 63;
  const int* base = adj + (size_t)list[s] * NN + kc + w * 512;
  unsigned long long* dst = (unsigned long long*)(pk + s * 256 + (kc >> 5) + w * 16);
#pragma unroll
  for (int i = 0; i < 8; ++i) {
    unsigned long long b = __ballot(base[i * 64 + l] > 0);  // bit l = key ...+i*64+l
    if (l == 0) dst[i] = b;
  }
}

// ---------------- Wh = embedding @ W, emitted as bf16 hi/lo split ----------------

__global__ __launch_bounds__(256) void wh_kernel(const float* __restrict__ emb,
                                                 const float* __restrict__ W,
                                                 ushortT* __restrict__ Whh,
                                                 ushortT* __restrict__ Whl) {
  __shared__ float Es[32 * 65];
  __shared__ float Ws[64 * 128];
  const int t = threadIdx.x;
  const int r0 = blockIdx.x * 32;
  const int rg = t >> 5;
  const int cg = t & 31;
  float4 acc[4] = {{0,0,0,0},{0,0,0,0},{0,0,0,0},{0,0,0,0}};
  for (int kc = 0; kc < DD; kc += 64) {
    __syncthreads();
    for (int i = 0; i < 8; ++i) {
      int idx = t + 256 * i;
      int r = idx >> 6, k = idx & 63;
      Es[r * 65 + k] = emb[(r0 + r) * DD + kc + k];
    }
    for (int i = 0; i < 8; ++i) {
      int idx = t + 256 * i;
      int kr = idx >> 5, c4 = (idx & 31) * 4;
      *(float4*)&Ws[kr * 128 + c4] = *(const float4*)&W[(kc + kr) * 128 + c4];
    }
    __syncthreads();
    for (int k = 0; k < 64; ++k) {
      float4 b = *(const float4*)&Ws[k * 128 + cg * 4];
#pragma unroll
      for (int i = 0; i < 4; ++i) {
        float a = Es[(rg * 4 + i) * 65 + k];
        acc[i].x += a * b.x; acc[i].y += a * b.y;
        acc[i].z += a * b.z; acc[i].w += a * b.w;
      }
    }
  }
#pragma unroll
  for (int i = 0; i < 4; ++i) {
    int row = r0 + rg * 4 + i;
    float v[4] = {acc[i].x, acc[i].y, acc[i].z, acc[i].w};
    ushort4 hh, ll;
    ushortT* hp = (ushortT*)&hh;
    ushortT* lp = (ushortT*)&ll;
#pragma unroll
    for (int k = 0; k < 4; ++k) {
      ushortT h = f2bf(v[k]);
      hp[k] = h;
      lp[k] = f2bf(v[k] - bf2f(h));
    }
    *(ushort4*)&Whh[row * FF + cg * 4] = hh;
    *(ushort4*)&Whl[row * FF + cg * 4] = ll;
  }
}

// ---------------- WhT = Whh^T (128 x 8192), 64x64 tiles (256 blocks) ----------------

__global__ __launch_bounds__(256) void transpose_kernel(const ushortT* __restrict__ A,
                                                        ushortT* __restrict__ At) {
  __shared__ ushortT tile[64 * 72];      // chunk-swizzled: (r, cb) at r*72 + ((cb^((r>>3)&7))*8)
  const int t = threadIdx.x;
  const int r0 = (blockIdx.x >> 1) * 64, c0 = (blockIdx.x & 1) * 64;
#pragma unroll
  for (int i = 0; i < 2; ++i) {
    int idx = t + 256 * i;
    int r = idx >> 3, cb = idx & 7;
    *(bf16x8*)&tile[r * 72 + ((cb ^ ((r >> 3) & 7)) * 8)] =
        *(const bf16x8*)&A[(size_t)(r0 + r) * FF + c0 + cb * 8];
  }
  __syncthreads();
#pragma unroll
  for (int i = 0; i < 2; ++i) {
    int idx = t + 256 * i;
    int f = idx >> 3, r8 = idx & 7;
    bf16x8 v;
#pragma unroll
    for (int u = 0; u < 8; ++u) {
      int row = r8 * 8 + u;
      v[u] = (short)tile[row * 72 + (((f >> 3) ^ ((row >> 3) & 7)) * 8) + (f & 7)];
    }
    *(bf16x8*)&At[(size_t)(c0 + f) * NN + r0 + r8 * 8] = v;
  }
}

// ---------------- MFMA flash attention: single-buffer LDS K, async-stage, 3 blocks/CU ----
// Block = 256 thr = 4 waves, 64 q-rows (wave w: rows w*16..+15), one 512-key chunk.
// K-tile (64 keys x 128 feats, hi+lo bf16) staged global->regs->LDS, SINGLE buffer
// (32 KB) + Ps (9.2 KB) = 42.2 KB LDS -> 3 blocks/CU (round-0's 64 KB dbuf capped at 2).
// Async-stage split (T14): issue tile t+1 global loads into regs at iter top (latency
// hides under QK/softmax/PV), then barrier(done reading) -> ds_write -> barrier(ready).
// NSPLIT=16 -> 816 active blocks ~ 3.2/CU fills the 3-slot residency (12 waves/CU,
// ~1.9x round-0 TLP). XOR chunk swizzle keeps B-frag ds_read_b128 2-way (free).
// Masks from packed bits (L2); V-frags from WhT (global, L2-resident per XCD).
// MFMA term order per (nt,ks) IDENTICAL to prior versions (qh*bh, ql*bh, qh*bl).
// Layouts: A[m=lane&15][k=quad*8+j]; B[k=quad*8+j][n=lane&15]; C/D row=quad*4+reg, col=lane&15.

__global__ __launch_bounds__(256, 3) void attn_kernel(
    const ushortT* __restrict__ Whh, const ushortT* __restrict__ Whl,
    const ushortT* __restrict__ WhT, const unsigned* __restrict__ pk,
    const int* __restrict__ list, const int* __restrict__ cntp,
    float* __restrict__ Opart, float* __restrict__ mpart, float* __restrict__ lpart) {
  __shared__ short Kh[64 * 128];
  __shared__ short Kl[64 * 128];
  __shared__ short Ps[4][16 * 72];
  __shared__ int nid[64];

  const int cnt = *cntp;
  const int qblk = blockIdx.x >> 4, chunk = blockIdx.x & 15;
  const int q0 = qblk * 64;
  if (q0 >= cnt) return;                 // uniform: whole block exits

  const int t = threadIdx.x;
  if (t < 64) nid[t] = list[min(q0 + t, cnt - 1)];  // tail rows dup cnt-1 (junk slots unused)
  __syncthreads();

  const int w = t >> 6, l = t & 63, quad = l >> 4, c = l & 15;

  // Q fragments in registers for the whole K loop (A-operand: row = c)
  const size_t qr = (size_t)nid[w * 16 + c] * FF;
  bf16x8 qh[4], ql[4];
#pragma unroll
  for (int ks = 0; ks < 4; ++ks) {
    qh[ks] = *(const bf16x8*)(Whh + qr + ks * 32 + quad * 8);
    ql[ks] = *(const bf16x8*)(Whl + qr + ks * 32 + quad * 8);
  }
  int prow[4];
#pragma unroll
  for (int r = 0; r < 4; ++r) prow[r] = min(q0 + w * 16 + quad * 4 + r, cnt - 1);

  float m[4], lr[4];
#pragma unroll
  for (int r = 0; r < 4; ++r) { m[r] = -1e30f; lr[r] = 0.f; }
  f32x4 O[8] = {{0,0,0,0},{0,0,0,0},{0,0,0,0},{0,0,0,0},
                {0,0,0,0},{0,0,0,0},{0,0,0,0},{0,0,0,0}};

  const int kt0 = chunk * KCHUNK;

  // prologue: stage tile 0 into the buffer
  bf16x8 sgh[4], sgl[4];
  {
    const ushortT* gh = Whh + (size_t)kt0 * FF;
    const ushortT* gl = Whl + (size_t)kt0 * FF;
#pragma unroll
    for (int i = 0; i < 4; ++i) {
      int idx = t + 256 * i;
      sgh[i] = *(const bf16x8*)(gh + idx * 8);
      sgl[i] = *(const bf16x8*)(gl + idx * 8);
    }
#pragma unroll
    for (int i = 0; i < 4; ++i) {
      int idx = t + 256 * i;
      int r = idx >> 4, cb = idx & 15;
      int off = r * 128 + ((cb ^ (r & 7)) * 8);
      *(bf16x8*)&Kh[off] = sgh[i];
      *(bf16x8*)&Kl[off] = sgl[i];
    }
  }
  __syncthreads();

  for (int it = 0; it < NITER; ++it) {
    const int kt = kt0 + it * 64;

    // ---- issue next K-tile global loads into regs (land during compute) ----
    if (it + 1 < NITER) {
      const ushortT* gh = Whh + (size_t)(kt + 64) * FF;
      const ushortT* gl = Whl + (size_t)(kt + 64) * FF;
#pragma unroll
      for (int i = 0; i < 4; ++i) {
        int idx = t + 256 * i;
        sgh[i] = *(const bf16x8*)(gh + idx * 8);
        sgl[i] = *(const bf16x8*)(gl + idx * 8);
      }
    }

    // ---- mask words: 64 bits per row, broadcast loads (L2) ----
    unsigned mw0[4], mw1[4];
#pragma unroll
    for (int r = 0; r < 4; ++r) {
      uint2 mm = *(const uint2*)(pk + (size_t)prow[r] * 256 + (kt >> 5));
      mw0[r] = mm.x; mw1[r] = mm.y;
    }

    // ---- S = Q.K^T over 4 key-16 tiles, 3-term hi/lo, K from LDS ----
    f32x4 sacc[4];
#pragma unroll
    for (int nt = 0; nt < 4; ++nt) {
      const int rb = (nt * 16 + c) * 128;
      f32x4 a = {0, 0, 0, 0};
#pragma unroll
      for (int ks = 0; ks < 4; ++ks) {
        const int off = rb + (((ks * 4 + quad) ^ (c & 7)) * 8);
        bf16x8 bh = *(const bf16x8*)&Kh[off];
        bf16x8 bl = *(const bf16x8*)&Kl[off];
        a = __builtin_amdgcn_mfma_f32_16x16x32_bf16(qh[ks], bh, a, 0, 0, 0);
        a = __builtin_amdgcn_mfma_f32_16x16x32_bf16(ql[ks], bh, a, 0, 0, 0);
        a = __builtin_amdgcn_mfma_f32_16x16x32_bf16(qh[ks], bl, a, 0, 0, 0);
      }
      sacc[nt] = a;
    }

    // ---- in-wave masked online softmax ----
    float rmax[4];
#pragma unroll
    for (int r = 0; r < 4; ++r) {
      float v = -1e30f;
#pragma unroll
      for (int nt = 0; nt < 4; ++nt) {
        unsigned bit = ((nt < 2 ? mw0[r] : mw1[r]) >> ((nt & 1) * 16 + c)) & 1u;
        v = fmaxf(v, bit ? sacc[nt][r] : -1e30f);
      }
      rmax[r] = v;
    }
#pragma unroll
    for (int mk = 1; mk <= 8; mk <<= 1)
#pragma unroll
      for (int r = 0; r < 4; ++r) rmax[r] = fmaxf(rmax[r], __shfl_xor(rmax[r], mk, 16));
    float sc[4], psum[4];
#pragma unroll
    for (int r = 0; r < 4; ++r) {
      float nm = fmaxf(m[r], rmax[r]);
      sc[r] = __expf(m[r] - nm);
      m[r] = nm;
      psum[r] = 0.f;
    }
#pragma unroll
    for (int nt = 0; nt < 4; ++nt)
#pragma unroll
      for (int r = 0; r < 4; ++r) {
        unsigned bit = ((nt < 2 ? mw0[r] : mw1[r]) >> ((nt & 1) * 16 + c)) & 1u;
        float p = bit ? __expf(sacc[nt][r] - m[r]) : 0.f;
        ushortT pb = f2bf(p);
        Ps[w][(quad * 4 + r) * 72 + nt * 16 + c] = (short)pb;
        psum[r] += bf2f(pb);
      }
#pragma unroll
    for (int mk = 1; mk <= 8; mk <<= 1)
#pragma unroll
      for (int r = 0; r < 4; ++r) psum[r] += __shfl_xor(psum[r], mk, 16);
#pragma unroll
    for (int r = 0; r < 4; ++r) lr[r] = lr[r] * sc[r] + psum[r];

    // ---- O rescale + PV (A from per-wave Ps, B from WhT global) ----
#pragma unroll
    for (int ft = 0; ft < 8; ++ft)
#pragma unroll
      for (int r = 0; r < 4; ++r) O[ft][r] *= sc[r];
    bf16x8 pa[2];
#pragma unroll
    for (int ks2 = 0; ks2 < 2; ++ks2)
      pa[ks2] = *(const bf16x8*)&Ps[w][c * 72 + ks2 * 32 + quad * 8];
#pragma unroll
    for (int ft = 0; ft < 8; ++ft) {
      const ushortT* vp = WhT + (size_t)(ft * 16 + c) * NN + kt + quad * 8;
#pragma unroll
      for (int ks2 = 0; ks2 < 2; ++ks2) {
        bf16x8 vb = *(const bf16x8*)(vp + ks2 * 32);
        O[ft] = __builtin_amdgcn_mfma_f32_16x16x32_bf16(pa[ks2], vb, O[ft], 0, 0, 0);
      }
    }

    // ---- stage the prefetched tile into LDS for next iter ----
    if (it + 1 < NITER) {
      __syncthreads();                   // all waves done reading Kh/Kl
#pragma unroll
      for (int i = 0; i < 4; ++i) {
        int idx = t + 256 * i;
        int r = idx >> 4, cb = idx & 15;
        int off = r * 128 + ((cb ^ (r & 7)) * 8);
        *(bf16x8*)&Kh[off] = sgh[i];
        *(bf16x8*)&Kl[off] = sgl[i];
      }
      __syncthreads();                   // buffer ready
    }
  }

  // ---- epilogue ----
  float* Op = Opart + (size_t)chunk * 4096 * FF;
#pragma unroll
  for (int ft = 0; ft < 8; ++ft)
#pragma unroll
    for (int r = 0; r < 4; ++r)
      Op[(size_t)(q0 + w * 16 + quad * 4 + r) * FF + ft * 16 + c] = O[ft][r];
  if (c == 0) {
#pragma unroll
    for (int r = 0; r < 4; ++r) {
      mpart[chunk * 4096 + q0 + w * 16 + quad * 4 + r] = m[r];
      lpart[chunk * 4096 + q0 + w * 16 + quad * 4 + r] = lr[r];
    }
  }
}

// ---------------- merge split-K partials, normalize, elu ----------------

__global__ __launch_bounds__(128) void combine_kernel(
    const float* __restrict__ Opart, const float* __restrict__ mpart,
    const float* __restrict__ lpart, float* __restrict__ h) {
  const int r = blockIdx.x;
  const int t = threadIdx.x;
  float mstar = -1e30f;
#pragma unroll
  for (int c = 0; c < NSPLIT; ++c) mstar = fmaxf(mstar, mpart[c * 4096 + r]);
  float lstar = 0.f, acc = 0.f;
#pragma unroll
  for (int c = 0; c < NSPLIT; ++c) {
    float wgt = __expf(mpart[c * 4096 + r] - mstar);
    lstar += wgt * lpart[c * 4096 + r];
    acc += wgt * Opart[((size_t)c * 4096 + r) * FF + t];
  }
  float v = acc / fmaxf(lstar, 1e-30f);
  h[r * FF + t] = v > 0.f ? v : expm1f(v);
}

// ---------------- gather by x, L2-normalize ----------------

__global__ __launch_bounds__(128) void out_kernel(const int* __restrict__ x,
                                                  const int* __restrict__ slot,
                                                  const float* __restrict__ h,
                                                  float* __restrict__ out) {
  const int b = blockIdx.x, t = threadIdx.x;
  const int s = slot[x[b]];
  float v = h[s * FF + t];
  float ss = v * v;
#pragma unroll
  for (int wd = 1; wd <= 32; wd <<= 1) ss += __shfl_xor(ss, wd);
  __shared__ float red[2];
  if ((t & 63) == 0) red[t >> 6] = ss;
  __syncthreads();
  float tot = red[0] + red[1];
  float scale = 1.f / fmaxf(sqrtf(tot), 1e-12f);
  out[b * FF + t] = v * scale;
}

// ---------------- launch ----------------

extern "C" void kernel_launch(void* const* d_in, const int* in_sizes, int n_in,
                              void* d_out, int out_size, void* d_ws, size_t ws_size,
                              hipStream_t stream) {
  const int*   x   = (const int*)d_in[0];
  const int*   adj = (const int*)d_in[1];
  const float* emb = (const float*)d_in[2];
  const float* W   = (const float*)d_in[3];
  float* out = (float*)d_out;

  char* base = (char*)d_ws;                              // ~44.6 MB total
  ushortT* Whh = (ushortT*)(base);                       //  0 .. 2 MB
  ushortT* Whl = (ushortT*)(base + 2097152);             //  2 .. 4 MB (dead after attn)
  float*   h   = (float*)(base + 2097152);               //  aliases Whl
  ushortT* WhT = (ushortT*)(base + 4194304);             //  4 .. 6 MB
  float* Opart = (float*)(base + 6291456);               //  6 .. 39.55 MB (16 chunks)
  float* mpart = (float*)(base + 39845888);
  float* lpart = (float*)(base + 40108032);
  unsigned* pk = (unsigned*)(base + 40370176);           //  4 MB packed adj bits
  int*   flags = (int*)(base + 44564480);
  int*   list  = (int*)(base + 44597248);
  int*   slot  = (int*)(base + 44613632);
  int*   cnt   = (int*)(base + 44646400);
  (void)in_sizes; (void)n_in; (void)out_size; (void)ws_size;

  hipLaunchKernelGGL(init_kernel,      dim3(NN / 256), dim3(256), 0, stream, flags, cnt);
  hipLaunchKernelGGL(scatter_kernel,   dim3(BB / 256), dim3(256), 0, stream, x, flags);
  hipLaunchKernelGGL(compact_kernel,   dim3(NN / 256), dim3(256), 0, stream, flags, cnt, list, slot);
  hipLaunchKernelGGL(pack_kernel,      dim3(4096 * 4), dim3(256), 0, stream, adj, list, cnt, pk);
  hipLaunchKernelGGL(wh_kernel,        dim3(NN / 32),  dim3(256), 0, stream, emb, W, Whh, Whl);
  hipLaunchKernelGGL(transpose_kernel, dim3((NN / 64) * 2), dim3(256), 0, stream, Whh, WhT);
  hipLaunchKernelGGL(attn_kernel,      dim3((BB / 64) * NSPLIT), dim3(256), 0, stream,
                     Whh, Whl, WhT, pk, list, cnt, Opart, mpart, lpart);
  hipLaunchKernelGGL(combine_kernel,   dim3(4096), dim3(128), 0, stream, Opart, mpart, lpart, h);
  hipLaunchKernelGGL(out_kernel,       dim3(BB),   dim3(128), 0, stream, x, slot, h, out);
}

// Round 3
// 439.415 us; speedup vs baseline: 1.3172x; 1.1202x over previous
//
#include <hip/hip_runtime.h>

#define NN 8192
#define DD 256
#define FF 128
#define BB 4096
#define NSPLIT 16
#define KCHUNK (NN / NSPLIT)   // 512 keys per split-K chunk
#define NITER (KCHUNK / 64)    // 8 key-tiles per chunk

typedef unsigned short ushortT;
typedef __attribute__((ext_vector_type(8))) short bf16x8;
typedef __attribute__((ext_vector_type(4))) float f32x4;

__device__ __forceinline__ ushortT f2bf(float f) {   // fp32 -> bf16 RNE
  unsigned u = __float_as_uint(f);
  return (ushortT)((u + 0x7FFFu + ((u >> 16) & 1u)) >> 16);
}
__device__ __forceinline__ float bf2f(ushortT h) {
  return __uint_as_float(((unsigned)h) << 16);
}

// ---------------- unique(x) compaction ----------------

__global__ __launch_bounds__(256) void init_kernel(int* flags, int* cnt) {
  int i = blockIdx.x * 256 + threadIdx.x;
  flags[i] = 0;
  if (i == 0) *cnt = 0;
}

__global__ __launch_bounds__(256) void scatter_kernel(const int* __restrict__ x, int* flags) {
  int b = blockIdx.x * 256 + threadIdx.x;
  flags[x[b]] = 1;
}

__global__ __launch_bounds__(256) void compact_kernel(const int* __restrict__ flags, int* cnt,
                                                      int* list, int* slot) {
  int i = blockIdx.x * 256 + threadIdx.x;
  if (flags[i]) {
    int pos = atomicAdd(cnt, 1);
    list[pos] = i;
    slot[i] = pos;
  }
}

// ---------------- pack adj rows of unique slots into bitmasks ----------------
// pk[s][k/32] bit (k&31) = adj[list[s]][k] > 0.  ~3.3 MB replacing a 107 MB
// latency-critical HBM stream in attn.

__global__ __launch_bounds__(256) void pack_kernel(const int* __restrict__ adj,
                                                   const int* __restrict__ list,
                                                   const int* __restrict__ cntp,
                                                   unsigned* __restrict__ pk) {
  const int s = blockIdx.x >> 2;
  const int kc = (blockIdx.x & 3) * 2048;
  if (s >= *cntp) return;                    // uniform per block
  const int w = threadIdx.x >> 6, l = threadIdx.x & 63;
  const int* base = adj + (size_t)list[s] * NN + kc + w * 512;
  unsigned long long* dst = (unsigned long long*)(pk + s * 256 + (kc >> 5) + w * 16);
#pragma unroll
  for (int i = 0; i < 8; ++i) {
    unsigned long long b = __ballot(base[i * 64 + l] > 0);  // bit l = key ...+i*64+l
    if (l == 0) dst[i] = b;
  }
}

// ---------------- Wh = embedding @ W, emitted as bf16 hi/lo split ----------------

__global__ __launch_bounds__(256) void wh_kernel(const float* __restrict__ emb,
                                                 const float* __restrict__ W,
                                                 ushortT* __restrict__ Whh,
                                                 ushortT* __restrict__ Whl) {
  __shared__ float Es[32 * 65];
  __shared__ float Ws[64 * 128];
  const int t = threadIdx.x;
  const int r0 = blockIdx.x * 32;
  const int rg = t >> 5;
  const int cg = t & 31;
  float4 acc[4] = {{0,0,0,0},{0,0,0,0},{0,0,0,0},{0,0,0,0}};
  for (int kc = 0; kc < DD; kc += 64) {
    __syncthreads();
    for (int i = 0; i < 8; ++i) {
      int idx = t + 256 * i;
      int r = idx >> 6, k = idx & 63;
      Es[r * 65 + k] = emb[(r0 + r) * DD + kc + k];
    }
    for (int i = 0; i < 8; ++i) {
      int idx = t + 256 * i;
      int kr = idx >> 5, c4 = (idx & 31) * 4;
      *(float4*)&Ws[kr * 128 + c4] = *(const float4*)&W[(kc + kr) * 128 + c4];
    }
    __syncthreads();
    for (int k = 0; k < 64; ++k) {
      float4 b = *(const float4*)&Ws[k * 128 + cg * 4];
#pragma unroll
      for (int i = 0; i < 4; ++i) {
        float a = Es[(rg * 4 + i) * 65 + k];
        acc[i].x += a * b.x; acc[i].y += a * b.y;
        acc[i].z += a * b.z; acc[i].w += a * b.w;
      }
    }
  }
#pragma unroll
  for (int i = 0; i < 4; ++i) {
    int row = r0 + rg * 4 + i;
    float v[4] = {acc[i].x, acc[i].y, acc[i].z, acc[i].w};
    ushort4 hh, ll;
    ushortT* hp = (ushortT*)&hh;
    ushortT* lp = (ushortT*)&ll;
#pragma unroll
    for (int k = 0; k < 4; ++k) {
      ushortT h = f2bf(v[k]);
      hp[k] = h;
      lp[k] = f2bf(v[k] - bf2f(h));
    }
    *(ushort4*)&Whh[row * FF + cg * 4] = hh;
    *(ushort4*)&Whl[row * FF + cg * 4] = ll;
  }
}

// ---------------- WhT = Whh^T (128 x 8192), 64x64 tiles (256 blocks) ----------------

__global__ __launch_bounds__(256) void transpose_kernel(const ushortT* __restrict__ A,
                                                        ushortT* __restrict__ At) {
  __shared__ ushortT tile[64 * 72];      // chunk-swizzled: (r, cb) at r*72 + ((cb^((r>>3)&7))*8)
  const int t = threadIdx.x;
  const int r0 = (blockIdx.x >> 1) * 64, c0 = (blockIdx.x & 1) * 64;
#pragma unroll
  for (int i = 0; i < 2; ++i) {
    int idx = t + 256 * i;
    int r = idx >> 3, cb = idx & 7;
    *(bf16x8*)&tile[r * 72 + ((cb ^ ((r >> 3) & 7)) * 8)] =
        *(const bf16x8*)&A[(size_t)(r0 + r) * FF + c0 + cb * 8];
  }
  __syncthreads();
#pragma unroll
  for (int i = 0; i < 2; ++i) {
    int idx = t + 256 * i;
    int f = idx >> 3, r8 = idx & 7;
    bf16x8 v;
#pragma unroll
    for (int u = 0; u < 8; ++u) {
      int row = r8 * 8 + u;
      v[u] = (short)tile[row * 72 + (((f >> 3) ^ ((row >> 3) & 7)) * 8) + (f & 7)];
    }
    *(bf16x8*)&At[(size_t)(c0 + f) * NN + r0 + r8 * 8] = v;
  }
}

// ---------------- MFMA flash attention: K AND V both LDS-staged, async-stage ----------------
// Block = 256 thr = 4 waves, 64 q-rows (wave w: rows w*16..+15), one 512-key chunk.
// Round-1 lesson: per-operand global loads where a 16-lane group touches 16 rows x 16 B
// are 16+ L2 transactions per instr -> latency catastrophe. Round<=2 still had exactly
// that pattern on the PV V-loads (WhT rows at 16 KB stride). Fix: stage the 16 KB V-tile
// (WhT[0..127][kt..kt+63]) into LDS coalesced (128 B rows), XOR-swizzled, shared by all
// 4 waves (4x reuse replaces 4x redundant scattered re-reads); PV B-frags become
// ds_read_b128 (2-way bank = free). Same async-stage split as K: issue K+V global loads
// at iter top (land under compute), ds_write between the two existing barriers.
// LDS = Kh 16K + Kl 16K + Vs 16K + Ps 9.2K = 58.6 KB -> 2 blocks/CU (occupancy proved
// non-binding in round 2; scattered VMEM is the lever).
// MFMA term order per (nt,ks) IDENTICAL (qh*bh, ql*bh, qh*bl); staged V data bit-identical
// to the old scattered loads -> numerics unchanged.
// Layouts: A[m=lane&15][k=quad*8+j]; B[k=quad*8+j][n=lane&15]; C/D row=quad*4+reg, col=lane&15.

__global__ __launch_bounds__(256, 2) void attn_kernel(
    const ushortT* __restrict__ Whh, const ushortT* __restrict__ Whl,
    const ushortT* __restrict__ WhT, const unsigned* __restrict__ pk,
    const int* __restrict__ list, const int* __restrict__ cntp,
    float* __restrict__ Opart, float* __restrict__ mpart, float* __restrict__ lpart) {
  __shared__ short Kh[64 * 128];
  __shared__ short Kl[64 * 128];
  __shared__ short Vs[128 * 64];         // [feat][key], chunk-XOR-swizzled
  __shared__ short Ps[4][16 * 72];
  __shared__ int nid[64];

  const int cnt = *cntp;
  const int qblk = blockIdx.x >> 4, chunk = blockIdx.x & 15;
  const int q0 = qblk * 64;
  if (q0 >= cnt) return;                 // uniform: whole block exits

  const int t = threadIdx.x;
  if (t < 64) nid[t] = list[min(q0 + t, cnt - 1)];  // tail rows dup cnt-1 (junk slots unused)
  __syncthreads();

  const int w = t >> 6, l = t & 63, quad = l >> 4, c = l & 15;

  // Q fragments in registers for the whole K loop (A-operand: row = c)
  const size_t qr = (size_t)nid[w * 16 + c] * FF;
  bf16x8 qh[4], ql[4];
#pragma unroll
  for (int ks = 0; ks < 4; ++ks) {
    qh[ks] = *(const bf16x8*)(Whh + qr + ks * 32 + quad * 8);
    ql[ks] = *(const bf16x8*)(Whl + qr + ks * 32 + quad * 8);
  }
  int prow[4];
#pragma unroll
  for (int r = 0; r < 4; ++r) prow[r] = min(q0 + w * 16 + quad * 4 + r, cnt - 1);

  float m[4], lr[4];
#pragma unroll
  for (int r = 0; r < 4; ++r) { m[r] = -1e30f; lr[r] = 0.f; }
  f32x4 O[8] = {{0,0,0,0},{0,0,0,0},{0,0,0,0},{0,0,0,0},
                {0,0,0,0},{0,0,0,0},{0,0,0,0},{0,0,0,0}};

  const int kt0 = chunk * KCHUNK;

  // prologue: stage tile 0 (K hi/lo + V) into LDS
  bf16x8 sgh[4], sgl[4], sgv[4];
  {
    const ushortT* gh = Whh + (size_t)kt0 * FF;
    const ushortT* gl = Whl + (size_t)kt0 * FF;
#pragma unroll
    for (int i = 0; i < 4; ++i) {
      int idx = t + 256 * i;
      sgh[i] = *(const bf16x8*)(gh + idx * 8);
      sgl[i] = *(const bf16x8*)(gl + idx * 8);
      int vr = idx >> 3, vcb = idx & 7;
      sgv[i] = *(const bf16x8*)(WhT + (size_t)vr * NN + kt0 + vcb * 8);
    }
#pragma unroll
    for (int i = 0; i < 4; ++i) {
      int idx = t + 256 * i;
      int r = idx >> 4, cb = idx & 15;
      int off = r * 128 + ((cb ^ (r & 7)) * 8);
      *(bf16x8*)&Kh[off] = sgh[i];
      *(bf16x8*)&Kl[off] = sgl[i];
      int vr = idx >> 3, vcb = idx & 7;
      *(bf16x8*)&Vs[vr * 64 + ((vcb ^ (vr & 7)) * 8)] = sgv[i];
    }
  }
  __syncthreads();

  for (int it = 0; it < NITER; ++it) {
    const int kt = kt0 + it * 64;

    // ---- issue next K/V-tile global loads into regs (land during compute) ----
    if (it + 1 < NITER) {
      const ushortT* gh = Whh + (size_t)(kt + 64) * FF;
      const ushortT* gl = Whl + (size_t)(kt + 64) * FF;
#pragma unroll
      for (int i = 0; i < 4; ++i) {
        int idx = t + 256 * i;
        sgh[i] = *(const bf16x8*)(gh + idx * 8);
        sgl[i] = *(const bf16x8*)(gl + idx * 8);
        int vr = idx >> 3, vcb = idx & 7;
        sgv[i] = *(const bf16x8*)(WhT + (size_t)vr * NN + (kt + 64) + vcb * 8);
      }
    }

    // ---- mask words: 64 bits per row, broadcast loads (L2) ----
    unsigned mw0[4], mw1[4];
#pragma unroll
    for (int r = 0; r < 4; ++r) {
      uint2 mm = *(const uint2*)(pk + (size_t)prow[r] * 256 + (kt >> 5));
      mw0[r] = mm.x; mw1[r] = mm.y;
    }

    // ---- S = Q.K^T over 4 key-16 tiles, 3-term hi/lo, K from LDS ----
    f32x4 sacc[4];
#pragma unroll
    for (int nt = 0; nt < 4; ++nt) {
      const int rb = (nt * 16 + c) * 128;
      f32x4 a = {0, 0, 0, 0};
#pragma unroll
      for (int ks = 0; ks < 4; ++ks) {
        const int off = rb + (((ks * 4 + quad) ^ (c & 7)) * 8);
        bf16x8 bh = *(const bf16x8*)&Kh[off];
        bf16x8 bl = *(const bf16x8*)&Kl[off];
        a = __builtin_amdgcn_mfma_f32_16x16x32_bf16(qh[ks], bh, a, 0, 0, 0);
        a = __builtin_amdgcn_mfma_f32_16x16x32_bf16(ql[ks], bh, a, 0, 0, 0);
        a = __builtin_amdgcn_mfma_f32_16x16x32_bf16(qh[ks], bl, a, 0, 0, 0);
      }
      sacc[nt] = a;
    }

    // ---- in-wave masked online softmax ----
    float rmax[4];
#pragma unroll
    for (int r = 0; r < 4; ++r) {
      float v = -1e30f;
#pragma unroll
      for (int nt = 0; nt < 4; ++nt) {
        unsigned bit = ((nt < 2 ? mw0[r] : mw1[r]) >> ((nt & 1) * 16 + c)) & 1u;
        v = fmaxf(v, bit ? sacc[nt][r] : -1e30f);
      }
      rmax[r] = v;
    }
#pragma unroll
    for (int mk = 1; mk <= 8; mk <<= 1)
#pragma unroll
      for (int r = 0; r < 4; ++r) rmax[r] = fmaxf(rmax[r], __shfl_xor(rmax[r], mk, 16));
    float sc[4], psum[4];
#pragma unroll
    for (int r = 0; r < 4; ++r) {
      float nm = fmaxf(m[r], rmax[r]);
      sc[r] = __expf(m[r] - nm);
      m[r] = nm;
      psum[r] = 0.f;
    }
#pragma unroll
    for (int nt = 0; nt < 4; ++nt)
#pragma unroll
      for (int r = 0; r < 4; ++r) {
        unsigned bit = ((nt < 2 ? mw0[r] : mw1[r]) >> ((nt & 1) * 16 + c)) & 1u;
        float p = bit ? __expf(sacc[nt][r] - m[r]) : 0.f;
        ushortT pb = f2bf(p);
        Ps[w][(quad * 4 + r) * 72 + nt * 16 + c] = (short)pb;
        psum[r] += bf2f(pb);
      }
#pragma unroll
    for (int mk = 1; mk <= 8; mk <<= 1)
#pragma unroll
      for (int r = 0; r < 4; ++r) psum[r] += __shfl_xor(psum[r], mk, 16);
#pragma unroll
    for (int r = 0; r < 4; ++r) lr[r] = lr[r] * sc[r] + psum[r];

    // ---- O rescale + PV (A from per-wave Ps, B from Vs LDS) ----
#pragma unroll
    for (int ft = 0; ft < 8; ++ft)
#pragma unroll
      for (int r = 0; r < 4; ++r) O[ft][r] *= sc[r];
    bf16x8 pa[2];
#pragma unroll
    for (int ks2 = 0; ks2 < 2; ++ks2)
      pa[ks2] = *(const bf16x8*)&Ps[w][c * 72 + ks2 * 32 + quad * 8];
#pragma unroll
    for (int ft = 0; ft < 8; ++ft) {
      const int vrow = ft * 16 + c;
#pragma unroll
      for (int ks2 = 0; ks2 < 2; ++ks2) {
        const int voff = vrow * 64 + (((ks2 * 4 + quad) ^ (c & 7)) * 8);
        bf16x8 vb = *(const bf16x8*)&Vs[voff];
        O[ft] = __builtin_amdgcn_mfma_f32_16x16x32_bf16(pa[ks2], vb, O[ft], 0, 0, 0);
      }
    }

    // ---- stage the prefetched tiles into LDS for next iter ----
    if (it + 1 < NITER) {
      __syncthreads();                   // all waves done reading Kh/Kl/Vs
#pragma unroll
      for (int i = 0; i < 4; ++i) {
        int idx = t + 256 * i;
        int r = idx >> 4, cb = idx & 15;
        int off = r * 128 + ((cb ^ (r & 7)) * 8);
        *(bf16x8*)&Kh[off] = sgh[i];
        *(bf16x8*)&Kl[off] = sgl[i];
        int vr = idx >> 3, vcb = idx & 7;
        *(bf16x8*)&Vs[vr * 64 + ((vcb ^ (vr & 7)) * 8)] = sgv[i];
      }
      __syncthreads();                   // buffers ready
    }
  }

  // ---- epilogue ----
  float* Op = Opart + (size_t)chunk * 4096 * FF;
#pragma unroll
  for (int ft = 0; ft < 8; ++ft)
#pragma unroll
    for (int r = 0; r < 4; ++r)
      Op[(size_t)(q0 + w * 16 + quad * 4 + r) * FF + ft * 16 + c] = O[ft][r];
  if (c == 0) {
#pragma unroll
    for (int r = 0; r < 4; ++r) {
      mpart[chunk * 4096 + q0 + w * 16 + quad * 4 + r] = m[r];
      lpart[chunk * 4096 + q0 + w * 16 + quad * 4 + r] = lr[r];
    }
  }
}

// ---------------- merge split-K partials, normalize, elu ----------------

__global__ __launch_bounds__(128) void combine_kernel(
    const float* __restrict__ Opart, const float* __restrict__ mpart,
    const float* __restrict__ lpart, float* __restrict__ h) {
  const int r = blockIdx.x;
  const int t = threadIdx.x;
  float mstar = -1e30f;
#pragma unroll
  for (int c = 0; c < NSPLIT; ++c) mstar = fmaxf(mstar, mpart[c * 4096 + r]);
  float lstar = 0.f, acc = 0.f;
#pragma unroll
  for (int c = 0; c < NSPLIT; ++c) {
    float wgt = __expf(mpart[c * 4096 + r] - mstar);
    lstar += wgt * lpart[c * 4096 + r];
    acc += wgt * Opart[((size_t)c * 4096 + r) * FF + t];
  }
  float v = acc / fmaxf(lstar, 1e-30f);
  h[r * FF + t] = v > 0.f ? v : expm1f(v);
}

// ---------------- gather by x, L2-normalize ----------------

__global__ __launch_bounds__(128) void out_kernel(const int* __restrict__ x,
                                                  const int* __restrict__ slot,
                                                  const float* __restrict__ h,
                                                  float* __restrict__ out) {
  const int b = blockIdx.x, t = threadIdx.x;
  const int s = slot[x[b]];
  float v = h[s * FF + t];
  float ss = v * v;
#pragma unroll
  for (int wd = 1; wd <= 32; wd <<= 1) ss += __shfl_xor(ss, wd);
  __shared__ float red[2];
  if ((t & 63) == 0) red[t >> 6] = ss;
  __syncthreads();
  float tot = red[0] + red[1];
  float scale = 1.f / fmaxf(sqrtf(tot), 1e-12f);
  out[b * FF + t] = v * scale;
}

// ---------------- launch ----------------

extern "C" void kernel_launch(void* const* d_in, const int* in_sizes, int n_in,
                              void* d_out, int out_size, void* d_ws, size_t ws_size,
                              hipStream_t stream) {
  const int*   x   = (const int*)d_in[0];
  const int*   adj = (const int*)d_in[1];
  const float* emb = (const float*)d_in[2];
  const float* W   = (const float*)d_in[3];
  float* out = (float*)d_out;

  char* base = (char*)d_ws;                              // ~44.6 MB total
  ushortT* Whh = (ushortT*)(base);                       //  0 .. 2 MB
  ushortT* Whl = (ushortT*)(base + 2097152);             //  2 .. 4 MB (dead after attn)
  float*   h   = (float*)(base + 2097152);               //  aliases Whl
  ushortT* WhT = (ushortT*)(base + 4194304);             //  4 .. 6 MB
  float* Opart = (float*)(base + 6291456);               //  6 .. 39.55 MB (16 chunks)
  float* mpart = (float*)(base + 39845888);
  float* lpart = (float*)(base + 40108032);
  unsigned* pk = (unsigned*)(base + 40370176);           //  4 MB packed adj bits
  int*   flags = (int*)(base + 44564480);
  int*   list  = (int*)(base + 44597248);
  int*   slot  = (int*)(base + 44613632);
  int*   cnt   = (int*)(base + 44646400);
  (void)in_sizes; (void)n_in; (void)out_size; (void)ws_size;

  hipLaunchKernelGGL(init_kernel,      dim3(NN / 256), dim3(256), 0, stream, flags, cnt);
  hipLaunchKernelGGL(scatter_kernel,   dim3(BB / 256), dim3(256), 0, stream, x, flags);
  hipLaunchKernelGGL(compact_kernel,   dim3(NN / 256), dim3(256), 0, stream, flags, cnt, list, slot);
  hipLaunchKernelGGL(pack_kernel,      dim3(4096 * 4), dim3(256), 0, stream, adj, list, cnt, pk);
  hipLaunchKernelGGL(wh_kernel,        dim3(NN / 32),  dim3(256), 0, stream, emb, W, Whh, Whl);
  hipLaunchKernelGGL(transpose_kernel, dim3((NN / 64) * 2), dim3(256), 0, stream, Whh, WhT);
  hipLaunchKernelGGL(attn_kernel,      dim3((BB / 64) * NSPLIT), dim3(256), 0, stream,
                     Whh, Whl, WhT, pk, list, cnt, Opart, mpart, lpart);
  hipLaunchKernelGGL(combine_kernel,   dim3(4096), dim3(128), 0, stream, Opart, mpart, lpart, h);
  hipLaunchKernelGGL(out_kernel,       dim3(BB),   dim3(128), 0, stream, x, slot, h, out);
}

// Round 4
// 435.036 us; speedup vs baseline: 1.3304x; 1.0101x over previous
//
#include <hip/hip_runtime.h>

#define NN 8192
#define DD 256
#define FF 128
#define BB 4096
#define NSPLIT 19
#define NTILES 128             // 8192 keys / 64

typedef unsigned short ushortT;
typedef __attribute__((ext_vector_type(8))) short bf16x8;
typedef __attribute__((ext_vector_type(4))) float f32x4;
typedef __attribute__((ext_vector_type(16))) float f32x16;

__device__ __forceinline__ ushortT f2bf(float f) {   // fp32 -> bf16 RNE
  unsigned u = __float_as_uint(f);
  return (ushortT)((u + 0x7FFFu + ((u >> 16) & 1u)) >> 16);
}
__device__ __forceinline__ float bf2f(ushortT h) {
  return __uint_as_float(((unsigned)h) << 16);
}

// ---------------- unique(x) compaction ----------------

__global__ __launch_bounds__(256) void init_kernel(int* flags, int* cnt) {
  int i = blockIdx.x * 256 + threadIdx.x;
  flags[i] = 0;
  if (i == 0) *cnt = 0;
}

__global__ __launch_bounds__(256) void scatter_kernel(const int* __restrict__ x, int* flags) {
  int b = blockIdx.x * 256 + threadIdx.x;
  flags[x[b]] = 1;
}

__global__ __launch_bounds__(256) void compact_kernel(const int* __restrict__ flags, int* cnt,
                                                      int* list, int* slot) {
  int i = blockIdx.x * 256 + threadIdx.x;
  if (flags[i]) {
    int pos = atomicAdd(cnt, 1);
    list[pos] = i;
    slot[i] = pos;
  }
}

// ---------------- pack adj rows of unique slots into bitmasks ----------------

__global__ __launch_bounds__(256) void pack_kernel(const int* __restrict__ adj,
                                                   const int* __restrict__ list,
                                                   const int* __restrict__ cntp,
                                                   unsigned* __restrict__ pk) {
  const int s = blockIdx.x >> 2;
  const int kc = (blockIdx.x & 3) * 2048;
  if (s >= *cntp) return;                    // uniform per block
  const int w = threadIdx.x >> 6, l = threadIdx.x & 63;
  const int* base = adj + (size_t)list[s] * NN + kc + w * 512;
  unsigned long long* dst = (unsigned long long*)(pk + s * 256 + (kc >> 5) + w * 16);
#pragma unroll
  for (int i = 0; i < 8; ++i) {
    unsigned long long b = __ballot(base[i * 64 + l] > 0);  // bit l = key ...+i*64+l
    if (l == 0) dst[i] = b;
  }
}

// ---------------- Wh = embedding @ W, emitted as bf16 hi/lo split ----------------

__global__ __launch_bounds__(256) void wh_kernel(const float* __restrict__ emb,
                                                 const float* __restrict__ W,
                                                 ushortT* __restrict__ Whh,
                                                 ushortT* __restrict__ Whl) {
  __shared__ float Es[32 * 65];
  __shared__ float Ws[64 * 128];
  const int t = threadIdx.x;
  const int r0 = blockIdx.x * 32;
  const int rg = t >> 5;
  const int cg = t & 31;
  float4 acc[4] = {{0,0,0,0},{0,0,0,0},{0,0,0,0},{0,0,0,0}};
  for (int kc = 0; kc < DD; kc += 64) {
    __syncthreads();
    for (int i = 0; i < 8; ++i) {
      int idx = t + 256 * i;
      int r = idx >> 6, k = idx & 63;
      Es[r * 65 + k] = emb[(r0 + r) * DD + kc + k];
    }
    for (int i = 0; i < 8; ++i) {
      int idx = t + 256 * i;
      int kr = idx >> 5, c4 = (idx & 31) * 4;
      *(float4*)&Ws[kr * 128 + c4] = *(const float4*)&W[(kc + kr) * 128 + c4];
    }
    __syncthreads();
    for (int k = 0; k < 64; ++k) {
      float4 b = *(const float4*)&Ws[k * 128 + cg * 4];
#pragma unroll
      for (int i = 0; i < 4; ++i) {
        float a = Es[(rg * 4 + i) * 65 + k];
        acc[i].x += a * b.x; acc[i].y += a * b.y;
        acc[i].z += a * b.z; acc[i].w += a * b.w;
      }
    }
  }
#pragma unroll
  for (int i = 0; i < 4; ++i) {
    int row = r0 + rg * 4 + i;
    float v[4] = {acc[i].x, acc[i].y, acc[i].z, acc[i].w};
    ushort4 hh, ll;
    ushortT* hp = (ushortT*)&hh;
    ushortT* lp = (ushortT*)&ll;
#pragma unroll
    for (int k = 0; k < 4; ++k) {
      ushortT h = f2bf(v[k]);
      hp[k] = h;
      lp[k] = f2bf(v[k] - bf2f(h));
    }
    *(ushort4*)&Whh[row * FF + cg * 4] = hh;
    *(ushort4*)&Whl[row * FF + cg * 4] = ll;
  }
}

// ---------------- WhT = Whh^T (128 x 8192), 64x64 tiles (256 blocks) ----------------

__global__ __launch_bounds__(256) void transpose_kernel(const ushortT* __restrict__ A,
                                                        ushortT* __restrict__ At) {
  __shared__ ushortT tile[64 * 72];
  const int t = threadIdx.x;
  const int r0 = (blockIdx.x >> 1) * 64, c0 = (blockIdx.x & 1) * 64;
#pragma unroll
  for (int i = 0; i < 2; ++i) {
    int idx = t + 256 * i;
    int r = idx >> 3, cb = idx & 7;
    *(bf16x8*)&tile[r * 72 + ((cb ^ ((r >> 3) & 7)) * 8)] =
        *(const bf16x8*)&A[(size_t)(r0 + r) * FF + c0 + cb * 8];
  }
  __syncthreads();
#pragma unroll
  for (int i = 0; i < 2; ++i) {
    int idx = t + 256 * i;
    int f = idx >> 3, r8 = idx & 7;
    bf16x8 v;
#pragma unroll
    for (int u = 0; u < 8; ++u) {
      int row = r8 * 8 + u;
      v[u] = (short)tile[row * 72 + (((f >> 3) ^ ((row >> 3) & 7)) * 8) + (f & 7)];
    }
    *(bf16x8*)&At[(size_t)(c0 + f) * NN + r0 + r8 * 8] = v;
  }
}

// ---------------- MFMA flash attention: swapped-operand 32x32x16, per-lane q ----------------
// Block = 256 thr = 4 waves, 128 q-rows (wave w: rows w*32..+31), chunk = NTILES/19 key-tiles.
// S^T = mfma32(A=K, B=Q): C col=lane&31 = q, row=(reg&3)+8*(reg>>2)+4*(lane>>5) = key.
// Each lane owns ONE q-column -> softmax fully in-lane + one shfl_xor(32) (no Ps LDS
// round-trip, no 4-step shuffle trees). P stays in regs (bf16, same f2bf RNE as before);
// one xor-32 word exchange builds PV B-frags: pa_s[j] = P[key=s*16+h*8+j][q] sourced from
// reg ((s&1)*2+h)*4+(j&3) of half (j>>2). PV computes O^T = mfma32(A=V^T from Vs, B=P^T):
// O col = q = lane&31 -> rescale uses the lane's own sc. 32x32x16 gives 2x FLOP per LDS
// B-byte vs 16x16x32 and the 128-q block amortizes K/V staging -> per-q LDS traffic ~2.2x
// lower. LDS = Kh 16K + Kl 16K + Vs 16K + nid = 49.7 KB; VGPR ~240 -> 2 blocks/CU.
// NSPLIT=19: 26 qblks x 19 = 494 active blocks ~ balanced 2/CU. MFMA product terms
// (Kh*Qh, Kh*Ql, Kl*Qh) unchanged from prior rounds.

__global__ __launch_bounds__(256, 2) void attn_kernel(
    const ushortT* __restrict__ Whh, const ushortT* __restrict__ Whl,
    const ushortT* __restrict__ WhT, const unsigned* __restrict__ pk,
    const int* __restrict__ list, const int* __restrict__ cntp,
    float* __restrict__ Opart, float* __restrict__ mpart, float* __restrict__ lpart) {
  __shared__ short Kh[64 * 128];
  __shared__ short Kl[64 * 128];
  __shared__ short Vs[128 * 64];         // [feat][key], chunk-XOR-swizzled
  __shared__ int nid[128];

  const int cnt = *cntp;
  const int qblk = blockIdx.x / NSPLIT, chunk = blockIdx.x % NSPLIT;
  const int q0 = qblk * 128;
  if (q0 >= cnt) return;                 // uniform: whole block exits

  const int t = threadIdx.x;
  if (t < 128) nid[t] = list[min(q0 + t, cnt - 1)];  // tail rows dup cnt-1
  __syncthreads();

  const int w = t >> 6, l = t & 63, h = l >> 5, lq = l & 31;

  // Q B-frags in registers: B[k=d=(h*8+j)+16*st][n=q=lq]
  const size_t qr = (size_t)nid[w * 32 + lq] * FF;
  bf16x8 qh[8], ql[8];
#pragma unroll
  for (int st = 0; st < 8; ++st) {
    qh[st] = *(const bf16x8*)(Whh + qr + st * 16 + h * 8);
    ql[st] = *(const bf16x8*)(Whl + qr + st * 16 + h * 8);
  }
  const int prow = min(q0 + w * 32 + lq, cnt - 1);

  float m = -1e30f, lr = 0.f;
  f32x16 O[4];
#pragma unroll
  for (int ft = 0; ft < 4; ++ft)
#pragma unroll
    for (int e = 0; e < 16; ++e) O[ft][e] = 0.f;

  const int ts = (chunk * NTILES) / NSPLIT;
  const int te = ((chunk + 1) * NTILES) / NSPLIT;

  // prologue: stage tile ts (K hi/lo + V) into LDS
  bf16x8 sgh[4], sgl[4], sgv[4];
  {
    const int kt0 = ts * 64;
    const ushortT* gh = Whh + (size_t)kt0 * FF;
    const ushortT* gl = Whl + (size_t)kt0 * FF;
#pragma unroll
    for (int i = 0; i < 4; ++i) {
      int idx = t + 256 * i;
      sgh[i] = *(const bf16x8*)(gh + idx * 8);
      sgl[i] = *(const bf16x8*)(gl + idx * 8);
      int vr = idx >> 3, vcb = idx & 7;
      sgv[i] = *(const bf16x8*)(WhT + (size_t)vr * NN + kt0 + vcb * 8);
    }
#pragma unroll
    for (int i = 0; i < 4; ++i) {
      int idx = t + 256 * i;
      int r = idx >> 4, cb = idx & 15;
      int off = r * 128 + ((cb ^ (r & 7)) * 8);
      *(bf16x8*)&Kh[off] = sgh[i];
      *(bf16x8*)&Kl[off] = sgl[i];
      int vr = idx >> 3, vcb = idx & 7;
      *(bf16x8*)&Vs[vr * 64 + ((vcb ^ (vr & 7)) * 8)] = sgv[i];
    }
  }
  __syncthreads();

  for (int it = ts; it < te; ++it) {
    const int kt = it * 64;

    // ---- issue next K/V-tile global loads into regs (land during compute) ----
    if (it + 1 < te) {
      const ushortT* gh = Whh + (size_t)(kt + 64) * FF;
      const ushortT* gl = Whl + (size_t)(kt + 64) * FF;
#pragma unroll
      for (int i = 0; i < 4; ++i) {
        int idx = t + 256 * i;
        sgh[i] = *(const bf16x8*)(gh + idx * 8);
        sgl[i] = *(const bf16x8*)(gl + idx * 8);
        int vr = idx >> 3, vcb = idx & 7;
        sgv[i] = *(const bf16x8*)(WhT + (size_t)vr * NN + (kt + 64) + vcb * 8);
      }
    }

    // ---- per-lane mask for own q-row: 64 bits ----
    const uint2 mm = *(const uint2*)(pk + (size_t)prow * 256 + (kt >> 5));

    // ---- S^T = K.Q over 2 key-32 tiles, 3-term hi/lo, K from LDS ----
    f32x16 s0, s1;
#pragma unroll
    for (int e = 0; e < 16; ++e) { s0[e] = 0.f; s1[e] = 0.f; }
#pragma unroll
    for (int st = 0; st < 8; ++st) {
      const int cb = st * 2 + h;
      const int o0 = lq * 128 + ((cb ^ (lq & 7)) * 8);
      bf16x8 ah = *(const bf16x8*)&Kh[o0];
      bf16x8 al = *(const bf16x8*)&Kl[o0];
      s0 = __builtin_amdgcn_mfma_f32_32x32x16_bf16(ah, qh[st], s0, 0, 0, 0);
      s0 = __builtin_amdgcn_mfma_f32_32x32x16_bf16(ah, ql[st], s0, 0, 0, 0);
      s0 = __builtin_amdgcn_mfma_f32_32x32x16_bf16(al, qh[st], s0, 0, 0, 0);
      const int r1 = 32 + lq;
      const int o1 = r1 * 128 + ((cb ^ (r1 & 7)) * 8);
      bf16x8 bh = *(const bf16x8*)&Kh[o1];
      bf16x8 bl = *(const bf16x8*)&Kl[o1];
      s1 = __builtin_amdgcn_mfma_f32_32x32x16_bf16(bh, qh[st], s1, 0, 0, 0);
      s1 = __builtin_amdgcn_mfma_f32_32x32x16_bf16(bh, ql[st], s1, 0, 0, 0);
      s1 = __builtin_amdgcn_mfma_f32_32x32x16_bf16(bl, qh[st], s1, 0, 0, 0);
    }

    // ---- in-lane masked online softmax (one q per lane) ----
    float rmx = -1e30f;
#pragma unroll
    for (int rg = 0; rg < 16; ++rg) {
      const int sh = (rg & 3) + 8 * (rg >> 2) + 4 * h;   // key within 32-tile
      rmx = fmaxf(rmx, ((mm.x >> sh) & 1u) ? s0[rg] : -1e30f);
      rmx = fmaxf(rmx, ((mm.y >> sh) & 1u) ? s1[rg] : -1e30f);
    }
    rmx = fmaxf(rmx, __shfl_xor(rmx, 32));
    const float nm = fmaxf(m, rmx);
    const float sc = __expf(m - nm);
    m = nm;
    float psum = 0.f;
    unsigned pw[16];                       // word k: regs 2k,2k+1 (ktile0: 0-7, ktile1: 8-15)
#pragma unroll
    for (int kk = 0; kk < 8; ++kk) {
      const int rgA = 2 * kk, rgB = 2 * kk + 1;
      const int shA = (rgA & 3) + 8 * (rgA >> 2) + 4 * h;
      const int shB = (rgB & 3) + 8 * (rgB >> 2) + 4 * h;
      float pA0 = ((mm.x >> shA) & 1u) ? __expf(s0[rgA] - m) : 0.f;
      float pB0 = ((mm.x >> shB) & 1u) ? __expf(s0[rgB] - m) : 0.f;
      ushortT qA0 = f2bf(pA0), qB0 = f2bf(pB0);
      psum += bf2f(qA0); psum += bf2f(qB0);
      pw[kk] = (unsigned)qA0 | ((unsigned)qB0 << 16);
      float pA1 = ((mm.y >> shA) & 1u) ? __expf(s1[rgA] - m) : 0.f;
      float pB1 = ((mm.y >> shB) & 1u) ? __expf(s1[rgB] - m) : 0.f;
      ushortT qA1 = f2bf(pA1), qB1 = f2bf(pB1);
      psum += bf2f(qA1); psum += bf2f(qB1);
      pw[8 + kk] = (unsigned)qA1 | ((unsigned)qB1 << 16);
    }
    psum += __shfl_xor(psum, 32);
    lr = lr * sc + psum;

    // ---- build P^T B-frags via one xor-32 exchange per word ----
    bf16x8 pa[4];
#pragma unroll
    for (int s = 0; s < 4; ++s) {
      const unsigned g0 = pw[4 * s], g1 = pw[4 * s + 1];
      const unsigned g2 = pw[4 * s + 2], g3 = pw[4 * s + 3];
      const unsigned k0 = h ? g2 : g0, k1 = h ? g3 : g1;    // own-half words
      const unsigned x0 = h ? g0 : g2, x1 = h ? g1 : g3;    // words to send
      const unsigned r0 = (unsigned)__shfl_xor((int)x0, 32);
      const unsigned r1 = (unsigned)__shfl_xor((int)x1, 32);
      union { unsigned u[4]; bf16x8 v; } uu;
      uu.u[0] = h ? r0 : k0;   // j0-3: from half-0 lane
      uu.u[1] = h ? r1 : k1;
      uu.u[2] = h ? k0 : r0;   // j4-7: from half-1 lane
      uu.u[3] = h ? k1 : r1;
      pa[s] = uu.v;
    }

    // ---- O^T rescale + PV: O^T = V^T . P^T (A from Vs LDS, B = pa) ----
#pragma unroll
    for (int ft = 0; ft < 4; ++ft)
#pragma unroll
      for (int e = 0; e < 16; ++e) O[ft][e] *= sc;
#pragma unroll
    for (int ft = 0; ft < 4; ++ft) {
      const int vr = ft * 32 + lq;
#pragma unroll
      for (int st = 0; st < 4; ++st) {
        const int cb = st * 2 + h;
        bf16x8 vb = *(const bf16x8*)&Vs[vr * 64 + ((cb ^ (vr & 7)) * 8)];
        O[ft] = __builtin_amdgcn_mfma_f32_32x32x16_bf16(vb, pa[st], O[ft], 0, 0, 0);
      }
    }

    // ---- stage the prefetched tiles into LDS for next iter ----
    if (it + 1 < te) {
      __syncthreads();                   // all waves done reading Kh/Kl/Vs
#pragma unroll
      for (int i = 0; i < 4; ++i) {
        int idx = t + 256 * i;
        int r = idx >> 4, cb = idx & 15;
        int off = r * 128 + ((cb ^ (r & 7)) * 8);
        *(bf16x8*)&Kh[off] = sgh[i];
        *(bf16x8*)&Kl[off] = sgl[i];
        int vr = idx >> 3, vcb = idx & 7;
        *(bf16x8*)&Vs[vr * 64 + ((vcb ^ (vr & 7)) * 8)] = sgv[i];
      }
      __syncthreads();                   // buffers ready
    }
  }

  // ---- epilogue: O^T regs -> Opart[q][f]; f = ft*32 + 8a + 4h + b ----
  float* Op = Opart + (size_t)chunk * 4096 * FF;
  const int qrow = q0 + w * 32 + lq;
#pragma unroll
  for (int ft = 0; ft < 4; ++ft)
#pragma unroll
    for (int a = 0; a < 4; ++a) {
      float4 v4 = {O[ft][4 * a], O[ft][4 * a + 1], O[ft][4 * a + 2], O[ft][4 * a + 3]};
      *(float4*)&Op[(size_t)qrow * FF + ft * 32 + a * 8 + h * 4] = v4;
    }
  if (h == 0) {
    mpart[chunk * 4096 + qrow] = m;
    lpart[chunk * 4096 + qrow] = lr;
  }
}

// ---------------- merge split-K partials, normalize, elu ----------------

__global__ __launch_bounds__(128) void combine_kernel(
    const float* __restrict__ Opart, const float* __restrict__ mpart,
    const float* __restrict__ lpart, float* __restrict__ h) {
  const int r = blockIdx.x;
  const int t = threadIdx.x;
  float mstar = -1e30f;
#pragma unroll
  for (int c = 0; c < NSPLIT; ++c) mstar = fmaxf(mstar, mpart[c * 4096 + r]);
  float lstar = 0.f, acc = 0.f;
#pragma unroll
  for (int c = 0; c < NSPLIT; ++c) {
    float wgt = __expf(mpart[c * 4096 + r] - mstar);
    lstar += wgt * lpart[c * 4096 + r];
    acc += wgt * Opart[((size_t)c * 4096 + r) * FF + t];
  }
  float v = acc / fmaxf(lstar, 1e-30f);
  h[r * FF + t] = v > 0.f ? v : expm1f(v);
}

// ---------------- gather by x, L2-normalize ----------------

__global__ __launch_bounds__(128) void out_kernel(const int* __restrict__ x,
                                                  const int* __restrict__ slot,
                                                  const float* __restrict__ h,
                                                  float* __restrict__ out) {
  const int b = blockIdx.x, t = threadIdx.x;
  const int s = slot[x[b]];
  float v = h[s * FF + t];
  float ss = v * v;
#pragma unroll
  for (int wd = 1; wd <= 32; wd <<= 1) ss += __shfl_xor(ss, wd);
  __shared__ float red[2];
  if ((t & 63) == 0) red[t >> 6] = ss;
  __syncthreads();
  float tot = red[0] + red[1];
  float scale = 1.f / fmaxf(sqrtf(tot), 1e-12f);
  out[b * FF + t] = v * scale;
}

// ---------------- launch ----------------

extern "C" void kernel_launch(void* const* d_in, const int* in_sizes, int n_in,
                              void* d_out, int out_size, void* d_ws, size_t ws_size,
                              hipStream_t stream) {
  const int*   x   = (const int*)d_in[0];
  const int*   adj = (const int*)d_in[1];
  const float* emb = (const float*)d_in[2];
  const float* W   = (const float*)d_in[3];
  float* out = (float*)d_out;

  char* base = (char*)d_ws;                              // ~51 MB total
  ushortT* Whh = (ushortT*)(base);                       //  0 .. 2 MB
  ushortT* Whl = (ushortT*)(base + 2097152);             //  2 .. 4 MB (dead after attn)
  float*   h   = (float*)(base + 2097152);               //  aliases Whl
  ushortT* WhT = (ushortT*)(base + 4194304);             //  4 .. 6 MB
  float* Opart = (float*)(base + 6291456);               //  6 .. 46.1 MB (19 chunks)
  float* mpart = (float*)(base + 46137344);
  float* lpart = (float*)(base + 46448640);
  unsigned* pk = (unsigned*)(base + 46759936);           //  4 MB packed adj bits
  int*   flags = (int*)(base + 50954240);
  int*   list  = (int*)(base + 50987008);
  int*   slot  = (int*)(base + 51019776);
  int*   cnt   = (int*)(base + 51052544);
  (void)in_sizes; (void)n_in; (void)out_size; (void)ws_size;

  hipLaunchKernelGGL(init_kernel,      dim3(NN / 256), dim3(256), 0, stream, flags, cnt);
  hipLaunchKernelGGL(scatter_kernel,   dim3(BB / 256), dim3(256), 0, stream, x, flags);
  hipLaunchKernelGGL(compact_kernel,   dim3(NN / 256), dim3(256), 0, stream, flags, cnt, list, slot);
  hipLaunchKernelGGL(pack_kernel,      dim3(4096 * 4), dim3(256), 0, stream, adj, list, cnt, pk);
  hipLaunchKernelGGL(wh_kernel,        dim3(NN / 32),  dim3(256), 0, stream, emb, W, Whh, Whl);
  hipLaunchKernelGGL(transpose_kernel, dim3((NN / 64) * 2), dim3(256), 0, stream, Whh, WhT);
  hipLaunchKernelGGL(attn_kernel,      dim3((BB / 128) * NSPLIT), dim3(256), 0, stream,
                     Whh, Whl, WhT, pk, list, cnt, Opart, mpart, lpart);
  hipLaunchKernelGGL(combine_kernel,   dim3(4096), dim3(128), 0, stream, Opart, mpart, lpart, h);
  hipLaunchKernelGGL(out_kernel,       dim3(BB),   dim3(128), 0, stream, x, slot, h, out);
}